// Round 11
// baseline (317.691 us; speedup 1.0000x reference)
//
#include <hip/hip_runtime.h>

// NoMCOutModel round 11: r10 (verified MFMA scan w/ fenced LDS handoff) +
//  (1) 2-bit t-quarter store swizzle p=(h&7)^(q_w<<1): produce b16 stores go
//      8-way -> 2-way (free). Scan compensates with the instruction-uniform
//      X(u)=((u>>2)<<1) XOR applied to cbuf/xj WRITE indices (n/m-independent
//      -> MFMA slot pairing intact; r9/r10 proved this class of compensation
//      was not r8's bug -- the handoff was, and r10's fences are kept).
//  (2) prep kernel folded in: each wave converts its own B-frag tiles into
//      ws at start (identical-byte cross-block races are benign; vmcnt(0)
//      fence before first use), bias loaded inline from br/bj. One dispatch.

namespace {

constexpr int B_ = 256, T_ = 256, M_ = 8, AUX_ = 32, H_ = 64;
constexpr float LOG2E = 1.4426950408889634f;

typedef __fp16 f16x2 __attribute__((ext_vector_type(2)));
typedef __fp16 f16x8 __attribute__((ext_vector_type(8)));
typedef float  f32x4 __attribute__((ext_vector_type(4)));
typedef int    i32x4 __attribute__((ext_vector_type(4)));

union V8 { f16x8 v; f16x2 p[4]; i32x4 i; };

#if __has_builtin(__builtin_amdgcn_exp2f)
#define EXP2(x) __builtin_amdgcn_exp2f(x)
#else
#define EXP2(x) exp2f(x)
#endif

template <int CTRL>
__device__ __forceinline__ float dpp_add(float v) {
    int t = __builtin_amdgcn_update_dpp(0, __builtin_bit_cast(int, v),
                                        CTRL, 0xf, 0xf, true);
    return v + __builtin_bit_cast(float, t);
}
__device__ __forceinline__ float sum16_all(float v) {
    v = dpp_add<0xB1>(v);   // quad_perm [1,0,3,2]
    v = dpp_add<0x4E>(v);   // quad_perm [2,3,0,1]
    v = dpp_add<0x141>(v);  // row_half_mirror
    v = dpp_add<0x140>(v);  // row_mirror
    return v;
}
__device__ __forceinline__ float sum64_uni(float v) {
    v = dpp_add<0x111>(v); v = dpp_add<0x112>(v); v = dpp_add<0x114>(v);
    v = dpp_add<0x118>(v); v = dpp_add<0x142>(v); v = dpp_add<0x143>(v);
    return __builtin_bit_cast(float,
        __builtin_amdgcn_readlane(__builtin_bit_cast(int, v), 63));
}

#define LDS_FENCE()  __asm__ volatile("s_waitcnt lgkmcnt(0)" ::: "memory")
#define VMEM_FENCE() __asm__ volatile("s_waitcnt vmcnt(0)" ::: "memory")
#define C_FENCE()    __asm__ volatile("" ::: "memory")

__global__ __launch_bounds__(1024, 4)
void nomc_main(const float* __restrict__ x_m, const float* __restrict__ x_a,
               const float* __restrict__ Wj, const float* __restrict__ bj,
               const float* __restrict__ Wr, const float* __restrict__ br,
               const float* __restrict__ Wo, const float* __restrict__ bo,
               const float* __restrict__ Wfc, const float* __restrict__ bfc,
               void* ws, float* __restrict__ out)
{
    const int b = blockIdx.x, tid = threadIdx.x;
    const int w = tid >> 6, l = tid & 63, q = l >> 4, l15 = l & 15;

    __shared__ __align__(16) __fp16 RT[16][8][64][8];   // 131072 B  RT[t][h>>3][k][(h&7)^((t>>2)<<1)]
    __shared__ __align__(16) __fp16 JT[16][64][8];      //  16384 B  JT[t][k][m^((t>>2)<<1)]
    __shared__ float sinv[16][64];                      //   4096 B  1/rowsum(R)
    __shared__ __align__(16) __fp16 xj[16][32];         //   1024 B  [t][m^X]=xm/s, [8..31]=0
    __shared__ float xm_lds[T_][M_];                    //   8192 B
    __shared__ __align__(16) __fp16 cbuf[64];           //    128 B  c-hat staging (A-frag)
    __shared__ float cfin_lds[H_];                      //    256 B
    // total 161152 <= 163840

    // wave w owns groups [g0, g0+ngrp); group = 4 tiles = one full softmax row.
    // waves 0..13 -> R rows (gg 0..63); waves 14,15 -> J rows (gg 64..71).
    const int ngrp = (w < 8) ? 5 : 4;
    const int g0   = (w < 8) ? w * 5 : 40 + (w - 8) * 4;
    char* wsb = (char*)ws;

    // ---- per-wave weight conversion: f32 W -> f16 B-frags in ws ----
    // ws[gt*1024 + lane*16]: f16x8, B[k=(lane>>4)*8+j][n=gt*16+(lane&15)], xLOG2E.
    // Each wave converts exactly the tiles it will consume (identical-byte
    // cross-block races on ws are benign).
    for (int c = 0; c < ngrp * 4; ++c) {
        const int gt = g0 * 4 + c;
        const int n = gt * 16 + l15;
        const float* src; int stride;
        if (gt < 256) { src = Wr + n;          stride = 4096; }
        else          { src = Wj + (n - 4096); stride = 512;  }
        V8 v;
#pragma unroll
        for (int j = 0; j < 4; ++j) {
            const float f0 = src[(q * 8 + 2 * j)     * stride] * LOG2E;
            const float f1 = src[(q * 8 + 2 * j + 1) * stride] * LOG2E;
            v.p[j] = __builtin_amdgcn_cvt_pkrtz(f0, f1);
        }
        *(i32x4*)(wsb + (size_t)gt * 1024 + l * 16) = v.i;
    }
    VMEM_FENCE();   // stores drained before this wave's produce loads from ws

    {   // stage x_m; zero the xj pad (slots 8..31 must be 0 every launch)
        const float* xmb = x_m + (size_t)b * T_ * M_;
        for (int i = tid; i < T_ * M_; i += 1024) (&xm_lds[0][0])[i] = xmb[i];
        for (int i = tid; i < 16 * 32; i += 1024) (&xj[0][0])[i] = (__fp16)0.f;
    }
    __syncthreads();

    const int swq = q << 1;                      // writer swizzle X = (t>>2)<<1, t = q*4+r

    float c0 = 0.f, c1 = 0.f, c2 = 0.f, c3 = 0.f;   // c[kt*16 + l15]

    for (int it = 0; it < 16; ++it) {
        // ================= produce: 16 timesteps of exp(logits) =================
        V8 af;
        {   // A-frag: row = l15 -> t = it*16+l15; k = q*8+j
            const float* xa = x_a + ((size_t)b * T_ + it * 16 + l15) * AUX_ + q * 8;
            const f32x4 x0 = *(const f32x4*)xa;
            const f32x4 x1 = *(const f32x4*)(xa + 4);
            af.p[0] = __builtin_amdgcn_cvt_pkrtz(x0.x, x0.y);
            af.p[1] = __builtin_amdgcn_cvt_pkrtz(x0.z, x0.w);
            af.p[2] = __builtin_amdgcn_cvt_pkrtz(x1.x, x1.y);
            af.p[3] = __builtin_amdgcn_cvt_pkrtz(x1.z, x1.w);
        }

        for (int g = 0; g < ngrp; ++g) {
            const int gg = g0 + g;                       // 0..63 R row h; 64..71 J row m
            float es0 = 0.f, es1 = 0.f, es2 = 0.f, es3 = 0.f;
#pragma unroll
            for (int tt = 0; tt < 4; ++tt) {
                const int gt = gg * 4 + tt;
                V8 bf; bf.i = *(const i32x4*)(wsb + (size_t)gt * 1024 + l * 16);
                const int n = gt * 16 + l15;
                const float bv = ((gt < 256) ? br[n] : bj[n - 4096]) * LOG2E;
                f32x4 acc = {bv, bv, bv, bv};
                acc = __builtin_amdgcn_mfma_f32_16x16x32_f16(af.v, bf.v, acc, 0, 0, 0);
                const float e0 = EXP2(acc[0]), e1 = EXP2(acc[1]);
                const float e2 = EXP2(acc[2]), e3 = EXP2(acc[3]);
                const int kk = (tt << 4) + l15;
                if (gg < 64) {
                    const int hb = gg >> 3, p = (gg & 7) ^ swq;   // 2-bit swizzle
                    RT[q * 4 + 0][hb][kk][p] = (__fp16)e0;
                    RT[q * 4 + 1][hb][kk][p] = (__fp16)e1;
                    RT[q * 4 + 2][hb][kk][p] = (__fp16)e2;
                    RT[q * 4 + 3][hb][kk][p] = (__fp16)e3;
                } else {
                    const int mp = (gg - 64) ^ swq;
                    JT[q * 4 + 0][kk][mp] = (__fp16)e0;
                    JT[q * 4 + 1][kk][mp] = (__fp16)e1;
                    JT[q * 4 + 2][kk][mp] = (__fp16)e2;
                    JT[q * 4 + 3][kk][mp] = (__fp16)e3;
                }
                es0 += e0; es1 += e1; es2 += e2; es3 += e3;
            }
            const float sr0 = sum16_all(es0), sr1 = sum16_all(es1);
            const float sr2 = sum16_all(es2), sr3 = sum16_all(es3);
            if (l15 == 0) {
                if (gg < 64) {
                    sinv[q * 4 + 0][gg] = __builtin_amdgcn_rcpf(sr0);
                    sinv[q * 4 + 1][gg] = __builtin_amdgcn_rcpf(sr1);
                    sinv[q * 4 + 2][gg] = __builtin_amdgcn_rcpf(sr2);
                    sinv[q * 4 + 3][gg] = __builtin_amdgcn_rcpf(sr3);
                } else {
                    const int m = gg - 64, mp = m ^ swq;
                    xj[q * 4 + 0][mp] = (__fp16)(xm_lds[it * 16 + q * 4 + 0][m] * __builtin_amdgcn_rcpf(sr0));
                    xj[q * 4 + 1][mp] = (__fp16)(xm_lds[it * 16 + q * 4 + 1][m] * __builtin_amdgcn_rcpf(sr1));
                    xj[q * 4 + 2][mp] = (__fp16)(xm_lds[it * 16 + q * 4 + 2][m] * __builtin_amdgcn_rcpf(sr2));
                    xj[q * 4 + 3][mp] = (__fp16)(xm_lds[it * 16 + q * 4 + 3][m] * __builtin_amdgcn_rcpf(sr3));
                }
            }
        }
        __syncthreads();

        // ================= scan: 16 serial MFMA matvecs (wave 15) =================
        if (w == 15) {
            for (int u = 0; u < 16; ++u) {
                const int Xu = ((u >> 2) & 3) << 1;      // matches producer swq at t=u
                // ALL lanes write (r10-verified handoff), index XOR-compensated
                const float cown = (q == 0) ? c0 : (q == 1) ? c1 : (q == 2) ? c2 : c3;
                cbuf[(l & ~7) | ((l & 7) ^ Xu)] = (__fp16)(cown * sinv[u][l]);
                LDS_FENCE();                             // write visible before reads
                V8 xjA; xjA.v = *(const f16x8*)&xj[u][q * 8];
                V8 A0;  A0.v  = *(const f16x8*)&cbuf[q * 8];
                V8 A1;  A1.v  = *(const f16x8*)&cbuf[32 + q * 8];
                float cn0, cn1, cn2, cn3;
#pragma unroll
                for (int kt = 0; kt < 4; ++kt) {
                    const int k = kt * 16 + l15;
                    V8 jB; jB.v = *(const f16x8*)&JT[u][k][0];
                    V8 b0; b0.v = *(const f16x8*)&RT[u][q][k][0];
                    V8 b1; b1.v = *(const f16x8*)&RT[u][4 + q][k][0];
                    f32x4 acc = {0.f, 0.f, 0.f, 0.f};
                    acc = __builtin_amdgcn_mfma_f32_16x16x32_f16(xjA.v, jB.v, acc, 0, 0, 0); // m_in
                    acc = __builtin_amdgcn_mfma_f32_16x16x32_f16(A0.v,  b0.v, acc, 0, 0, 0); // h 0..31
                    acc = __builtin_amdgcn_mfma_f32_16x16x32_f16(A1.v,  b1.v, acc, 0, 0, 0); // h 32..63
                    const float cv = acc[0];             // D rows all equal; col = l15
                    if (kt == 0) cn0 = cv; else if (kt == 1) cn1 = cv;
                    else if (kt == 2) cn2 = cv; else cn3 = cv;
                }
                c0 = cn0; c1 = cn1; c2 = cn2; c3 = cn3;
                C_FENCE();                               // no cross-iteration hoisting
            }
        }
        __syncthreads();
    }

    // ---- epilogue: out = (sigmoid(xa_T@Wo+bo) * c_T) @ Wfc + bfc ----
    if (w == 15) {
        const float cown = (q == 0) ? c0 : (q == 1) ? c1 : (q == 2) ? c2 : c3;
        cfin_lds[l] = cown;                              // all-lane write
        LDS_FENCE();
        const float* xa = x_a + ((size_t)b * T_ + (T_ - 1)) * AUX_;
        float L = bo[l];
#pragma unroll
        for (int a = 0; a < AUX_; ++a) L = fmaf(xa[a], Wo[a * H_ + l], L);
        const float o = 1.0f / (1.0f + __expf(-L));
        const float cfin = cfin_lds[l];
        float p = (o * cfin) * Wfc[l];
        p = sum64_uni(p);
        if (l == 0) out[b] = p + bfc[0];
        out[B_ + b * H_ + l] = cfin;                     // c_final, coalesced
    }
}

} // namespace

extern "C" void kernel_launch(void* const* d_in, const int* in_sizes, int n_in,
                              void* d_out, int out_size, void* d_ws, size_t ws_size,
                              hipStream_t stream) {
    const float* x_m = (const float*)d_in[0];
    const float* x_a = (const float*)d_in[1];
    const float* Wj  = (const float*)d_in[2];
    const float* bj  = (const float*)d_in[3];
    const float* Wr  = (const float*)d_in[4];
    const float* br  = (const float*)d_in[5];
    const float* Wo  = (const float*)d_in[6];
    const float* bo  = (const float*)d_in[7];
    const float* Wfc = (const float*)d_in[8];
    const float* bfc = (const float*)d_in[9];
    float* out = (float*)d_out;

    hipLaunchKernelGGL(nomc_main, dim3(B_), dim3(1024), 0, stream,
                       x_m, x_a, Wj, bj, Wr, br, Wo, bo, Wfc, bfc, d_ws, out);
}

// Round 12
// 292.745 us; speedup vs baseline: 1.0852x; 1.0852x over previous
//
#include <hip/hip_runtime.h>

// NoMCOutModel round 12: merge of the two verified wins.
//  - r10's two-kernel structure: prep converts W -> f16 B-frags + bias into
//    ws ONCE (r11 proved the ~55us total-main gap is fixed harness overhead,
//    NOT the prep dispatch; inlining the conversion cost main +60us).
//  - r11's 2-bit t-quarter store swizzle p=(h&7)^(q_w<<1): produce b16
//    stores 8-way -> 2-way (conflicts 3.09e7 -> 1.18e7, verified correct).
//    Scan compensates via instruction-uniform XOR on cbuf/xj WRITE indices.
//  - r10's fenced all-lane cbuf handoff kept verbatim (the r8/r9 bug).

namespace {

constexpr int B_ = 256, T_ = 256, M_ = 8, AUX_ = 32, H_ = 64;
constexpr int NTILE = 288;               // (64*64 + 8*64)/16 logit col-tiles
constexpr float LOG2E = 1.4426950408889634f;

typedef __fp16 f16x2 __attribute__((ext_vector_type(2)));
typedef __fp16 f16x8 __attribute__((ext_vector_type(8)));
typedef float  f32x4 __attribute__((ext_vector_type(4)));
typedef int    i32x4 __attribute__((ext_vector_type(4)));

union V8 { f16x8 v; f16x2 p[4]; i32x4 i; };

#if __has_builtin(__builtin_amdgcn_exp2f)
#define EXP2(x) __builtin_amdgcn_exp2f(x)
#else
#define EXP2(x) exp2f(x)
#endif

template <int CTRL>
__device__ __forceinline__ float dpp_add(float v) {
    int t = __builtin_amdgcn_update_dpp(0, __builtin_bit_cast(int, v),
                                        CTRL, 0xf, 0xf, true);
    return v + __builtin_bit_cast(float, t);
}
__device__ __forceinline__ float sum16_all(float v) {
    v = dpp_add<0xB1>(v);   // quad_perm [1,0,3,2]
    v = dpp_add<0x4E>(v);   // quad_perm [2,3,0,1]
    v = dpp_add<0x141>(v);  // row_half_mirror
    v = dpp_add<0x140>(v);  // row_mirror
    return v;
}
__device__ __forceinline__ float sum64_uni(float v) {
    v = dpp_add<0x111>(v); v = dpp_add<0x112>(v); v = dpp_add<0x114>(v);
    v = dpp_add<0x118>(v); v = dpp_add<0x142>(v); v = dpp_add<0x143>(v);
    return __builtin_bit_cast(float,
        __builtin_amdgcn_readlane(__builtin_bit_cast(int, v), 63));
}

#define LDS_FENCE() __asm__ volatile("s_waitcnt lgkmcnt(0)" ::: "memory")
#define C_FENCE()   __asm__ volatile("" ::: "memory")

// ---------------- prep: W -> f16 MFMA B-frag layout in ws ----------------
// ws[gt*1024 + lane*16] : f16x8 frag, B[k = (lane>>4)*8 + j][n = gt*16+(lane&15)]
// ws + 288*1024 : float bias[4608] (log2e-scaled)
__global__ __launch_bounds__(64)
void nomc_prep(const float* __restrict__ Wj, const float* __restrict__ bj,
               const float* __restrict__ Wr, const float* __restrict__ br,
               void* __restrict__ ws)
{
    const int gt = blockIdx.x;           // 0..287
    const int l = threadIdx.x, q = l >> 4, l15 = l & 15;
    const float* src; const float* bsrc; int stride;
    if (gt < 256) { const int n = gt * 16 + l15;        src = Wr + n; bsrc = br + n; stride = 4096; }
    else          { const int n = (gt - 256) * 16 + l15; src = Wj + n; bsrc = bj + n; stride = 512; }
    V8 v;
#pragma unroll
    for (int j = 0; j < 4; ++j) {
        const float f0 = src[(q * 8 + 2 * j)     * stride] * LOG2E;
        const float f1 = src[(q * 8 + 2 * j + 1) * stride] * LOG2E;
        v.p[j] = __builtin_amdgcn_cvt_pkrtz(f0, f1);
    }
    *(i32x4*)((char*)ws + (size_t)gt * 1024 + l * 16) = v.i;
    if (l < 16)
        ((float*)((char*)ws + NTILE * 1024))[gt * 16 + l] = bsrc[0] * LOG2E;
}

// ---------------- main ----------------
__global__ __launch_bounds__(1024, 4)
void nomc_main(const float* __restrict__ x_m, const float* __restrict__ x_a,
               const float* __restrict__ Wo, const float* __restrict__ bo,
               const float* __restrict__ Wfc, const float* __restrict__ bfc,
               const void* __restrict__ ws, float* __restrict__ out)
{
    const int b = blockIdx.x, tid = threadIdx.x;
    const int w = tid >> 6, l = tid & 63, q = l >> 4, l15 = l & 15;

    __shared__ __align__(16) __fp16 RT[16][8][64][8];   // 131072 B  RT[t][h>>3][k][(h&7)^((t>>2)<<1)]
    __shared__ __align__(16) __fp16 JT[16][64][8];      //  16384 B  JT[t][k][m^((t>>2)<<1)]
    __shared__ float sinv[16][64];                      //   4096 B  1/rowsum(R)
    __shared__ __align__(16) __fp16 xj[16][32];         //   1024 B  [t][m^X]=xm/s, [8..31]=0
    __shared__ float xm_lds[T_][M_];                    //   8192 B
    __shared__ __align__(16) __fp16 cbuf[64];           //    128 B  c-hat staging (A-frag)
    __shared__ float cfin_lds[H_];                      //    256 B
    // total 161152 <= 163840

    {   // stage x_m; zero the xj pad (slots 8..31 must be 0 every launch)
        const float* xmb = x_m + (size_t)b * T_ * M_;
        for (int i = tid; i < T_ * M_; i += 1024) (&xm_lds[0][0])[i] = xmb[i];
        for (int i = tid; i < 16 * 32; i += 1024) (&xj[0][0])[i] = (__fp16)0.f;
    }
    __syncthreads();

    // wave w owns groups [g0, g0+ngrp); group = 4 tiles = one full softmax row.
    // waves 0..13 -> R rows (gg 0..63); waves 14,15 -> J rows (gg 64..71).
    const int ngrp = (w < 8) ? 5 : 4;
    const int g0   = (w < 8) ? w * 5 : 40 + (w - 8) * 4;
    const char* wsb = (const char*)ws;
    const float* wbias = (const float*)(wsb + NTILE * 1024);

    const int swq = q << 1;                      // writer swizzle X = (t>>2)<<1, t = q*4+r

    float c0 = 0.f, c1 = 0.f, c2 = 0.f, c3 = 0.f;   // c[kt*16 + l15]

    for (int it = 0; it < 16; ++it) {
        // ================= produce: 16 timesteps of exp(logits) =================
        V8 af;
        {   // A-frag: row = l15 -> t = it*16+l15; k = q*8+j
            const float* xa = x_a + ((size_t)b * T_ + it * 16 + l15) * AUX_ + q * 8;
            const f32x4 x0 = *(const f32x4*)xa;
            const f32x4 x1 = *(const f32x4*)(xa + 4);
            af.p[0] = __builtin_amdgcn_cvt_pkrtz(x0.x, x0.y);
            af.p[1] = __builtin_amdgcn_cvt_pkrtz(x0.z, x0.w);
            af.p[2] = __builtin_amdgcn_cvt_pkrtz(x1.x, x1.y);
            af.p[3] = __builtin_amdgcn_cvt_pkrtz(x1.z, x1.w);
        }

        for (int g = 0; g < ngrp; ++g) {
            const int gg = g0 + g;                       // 0..63 R row h; 64..71 J row m
            float es0 = 0.f, es1 = 0.f, es2 = 0.f, es3 = 0.f;
#pragma unroll
            for (int tt = 0; tt < 4; ++tt) {
                const int gt = gg * 4 + tt;
                V8 bf; bf.i = *(const i32x4*)(wsb + (size_t)gt * 1024 + l * 16);
                const float bv = wbias[gt * 16 + l15];
                f32x4 acc = {bv, bv, bv, bv};
                acc = __builtin_amdgcn_mfma_f32_16x16x32_f16(af.v, bf.v, acc, 0, 0, 0);
                const float e0 = EXP2(acc[0]), e1 = EXP2(acc[1]);
                const float e2 = EXP2(acc[2]), e3 = EXP2(acc[3]);
                const int kk = (tt << 4) + l15;
                if (gg < 64) {
                    const int hb = gg >> 3, p = (gg & 7) ^ swq;   // 2-bit swizzle
                    RT[q * 4 + 0][hb][kk][p] = (__fp16)e0;
                    RT[q * 4 + 1][hb][kk][p] = (__fp16)e1;
                    RT[q * 4 + 2][hb][kk][p] = (__fp16)e2;
                    RT[q * 4 + 3][hb][kk][p] = (__fp16)e3;
                } else {
                    const int mp = (gg - 64) ^ swq;
                    JT[q * 4 + 0][kk][mp] = (__fp16)e0;
                    JT[q * 4 + 1][kk][mp] = (__fp16)e1;
                    JT[q * 4 + 2][kk][mp] = (__fp16)e2;
                    JT[q * 4 + 3][kk][mp] = (__fp16)e3;
                }
                es0 += e0; es1 += e1; es2 += e2; es3 += e3;
            }
            const float sr0 = sum16_all(es0), sr1 = sum16_all(es1);
            const float sr2 = sum16_all(es2), sr3 = sum16_all(es3);
            if (l15 == 0) {
                if (gg < 64) {
                    sinv[q * 4 + 0][gg] = __builtin_amdgcn_rcpf(sr0);
                    sinv[q * 4 + 1][gg] = __builtin_amdgcn_rcpf(sr1);
                    sinv[q * 4 + 2][gg] = __builtin_amdgcn_rcpf(sr2);
                    sinv[q * 4 + 3][gg] = __builtin_amdgcn_rcpf(sr3);
                } else {
                    const int m = gg - 64, mp = m ^ swq;
                    xj[q * 4 + 0][mp] = (__fp16)(xm_lds[it * 16 + q * 4 + 0][m] * __builtin_amdgcn_rcpf(sr0));
                    xj[q * 4 + 1][mp] = (__fp16)(xm_lds[it * 16 + q * 4 + 1][m] * __builtin_amdgcn_rcpf(sr1));
                    xj[q * 4 + 2][mp] = (__fp16)(xm_lds[it * 16 + q * 4 + 2][m] * __builtin_amdgcn_rcpf(sr2));
                    xj[q * 4 + 3][mp] = (__fp16)(xm_lds[it * 16 + q * 4 + 3][m] * __builtin_amdgcn_rcpf(sr3));
                }
            }
        }
        __syncthreads();

        // ================= scan: 16 serial MFMA matvecs (wave 15) =================
        if (w == 15) {
            for (int u = 0; u < 16; ++u) {
                const int Xu = ((u >> 2) & 3) << 1;      // matches producer swq at t=u
                // ALL lanes write (r10-verified handoff), index XOR-compensated
                const float cown = (q == 0) ? c0 : (q == 1) ? c1 : (q == 2) ? c2 : c3;
                cbuf[(l & ~7) | ((l & 7) ^ Xu)] = (__fp16)(cown * sinv[u][l]);
                LDS_FENCE();                             // write visible before reads
                V8 xjA; xjA.v = *(const f16x8*)&xj[u][q * 8];
                V8 A0;  A0.v  = *(const f16x8*)&cbuf[q * 8];
                V8 A1;  A1.v  = *(const f16x8*)&cbuf[32 + q * 8];
                float cn0, cn1, cn2, cn3;
#pragma unroll
                for (int kt = 0; kt < 4; ++kt) {
                    const int k = kt * 16 + l15;
                    V8 jB; jB.v = *(const f16x8*)&JT[u][k][0];
                    V8 b0; b0.v = *(const f16x8*)&RT[u][q][k][0];
                    V8 b1; b1.v = *(const f16x8*)&RT[u][4 + q][k][0];
                    f32x4 acc = {0.f, 0.f, 0.f, 0.f};
                    acc = __builtin_amdgcn_mfma_f32_16x16x32_f16(xjA.v, jB.v, acc, 0, 0, 0); // m_in
                    acc = __builtin_amdgcn_mfma_f32_16x16x32_f16(A0.v,  b0.v, acc, 0, 0, 0); // h 0..31
                    acc = __builtin_amdgcn_mfma_f32_16x16x32_f16(A1.v,  b1.v, acc, 0, 0, 0); // h 32..63
                    const float cv = acc[0];             // D rows all equal; col = l15
                    if (kt == 0) cn0 = cv; else if (kt == 1) cn1 = cv;
                    else if (kt == 2) cn2 = cv; else cn3 = cv;
                }
                c0 = cn0; c1 = cn1; c2 = cn2; c3 = cn3;
                C_FENCE();                               // no cross-iteration hoisting
            }
        }
        __syncthreads();
    }

    // ---- epilogue: out = (sigmoid(xa_T@Wo+bo) * c_T) @ Wfc + bfc ----
    if (w == 15) {
        const float cown = (q == 0) ? c0 : (q == 1) ? c1 : (q == 2) ? c2 : c3;
        cfin_lds[l] = cown;                              // all-lane write
        LDS_FENCE();
        const float* xa = x_a + ((size_t)b * T_ + (T_ - 1)) * AUX_;
        float L = bo[l];
#pragma unroll
        for (int a = 0; a < AUX_; ++a) L = fmaf(xa[a], Wo[a * H_ + l], L);
        const float o = 1.0f / (1.0f + __expf(-L));
        const float cfin = cfin_lds[l];
        float p = (o * cfin) * Wfc[l];
        p = sum64_uni(p);
        if (l == 0) out[b] = p + bfc[0];
        out[B_ + b * H_ + l] = cfin;                     // c_final, coalesced
    }
}

} // namespace

extern "C" void kernel_launch(void* const* d_in, const int* in_sizes, int n_in,
                              void* d_out, int out_size, void* d_ws, size_t ws_size,
                              hipStream_t stream) {
    const float* x_m = (const float*)d_in[0];
    const float* x_a = (const float*)d_in[1];
    const float* Wj  = (const float*)d_in[2];
    const float* bj  = (const float*)d_in[3];
    const float* Wr  = (const float*)d_in[4];
    const float* br  = (const float*)d_in[5];
    const float* Wo  = (const float*)d_in[6];
    const float* bo  = (const float*)d_in[7];
    const float* Wfc = (const float*)d_in[8];
    const float* bfc = (const float*)d_in[9];
    float* out = (float*)d_out;

    hipLaunchKernelGGL(nomc_prep, dim3(NTILE), dim3(64), 0, stream,
                       Wj, bj, Wr, br, d_ws);
    hipLaunchKernelGGL(nomc_main, dim3(B_), dim3(1024), 0, stream,
                       x_m, x_a, Wo, bo, Wfc, bfc, d_ws, out);
}

// Round 13
// 281.186 us; speedup vs baseline: 1.1298x; 1.0411x over previous
//
#include <hip/hip_runtime.h>

// NoMCOutModel round 13: r10 exact (plain layout; r12 proved the store
// swizzle is a net loss -- produce-store conflicts are absorbed by 15-wave
// TLP, off the critical path), plus a latency-directed scan-step
// restructure:
//  (1) junction reads + 4 junction MFMAs hoisted between the c-hat ds_write
//      and the fence (independent of cbuf; hides the write drain),
//  (2) post-fence R-chain depth 3 -> 2 (accJ precomputed),
//  (3) sinv[u+1] software-pipelined behind the MFMAs.
// Keeps r10's verified fenced all-lane cbuf handoff and two-kernel split
// (r11: the ~55us total-main gap is fixed harness overhead, not prep).

namespace {

constexpr int B_ = 256, T_ = 256, M_ = 8, AUX_ = 32, H_ = 64;
constexpr int NTILE = 288;               // (64*64 + 8*64)/16 logit col-tiles
constexpr float LOG2E = 1.4426950408889634f;

typedef __fp16 f16x2 __attribute__((ext_vector_type(2)));
typedef __fp16 f16x8 __attribute__((ext_vector_type(8)));
typedef float  f32x4 __attribute__((ext_vector_type(4)));
typedef int    i32x4 __attribute__((ext_vector_type(4)));

union V8 { f16x8 v; f16x2 p[4]; i32x4 i; };

#if __has_builtin(__builtin_amdgcn_exp2f)
#define EXP2(x) __builtin_amdgcn_exp2f(x)
#else
#define EXP2(x) exp2f(x)
#endif

#define MFMA16(A, Bv, C) __builtin_amdgcn_mfma_f32_16x16x32_f16((A), (Bv), (C), 0, 0, 0)

template <int CTRL>
__device__ __forceinline__ float dpp_add(float v) {
    int t = __builtin_amdgcn_update_dpp(0, __builtin_bit_cast(int, v),
                                        CTRL, 0xf, 0xf, true);
    return v + __builtin_bit_cast(float, t);
}
__device__ __forceinline__ float sum16_all(float v) {
    v = dpp_add<0xB1>(v);   // quad_perm [1,0,3,2]
    v = dpp_add<0x4E>(v);   // quad_perm [2,3,0,1]
    v = dpp_add<0x141>(v);  // row_half_mirror
    v = dpp_add<0x140>(v);  // row_mirror
    return v;
}
__device__ __forceinline__ float sum64_uni(float v) {
    v = dpp_add<0x111>(v); v = dpp_add<0x112>(v); v = dpp_add<0x114>(v);
    v = dpp_add<0x118>(v); v = dpp_add<0x142>(v); v = dpp_add<0x143>(v);
    return __builtin_bit_cast(float,
        __builtin_amdgcn_readlane(__builtin_bit_cast(int, v), 63));
}

#define LDS_FENCE() __asm__ volatile("s_waitcnt lgkmcnt(0)" ::: "memory")
#define C_FENCE()   __asm__ volatile("" ::: "memory")

// ---------------- prep: W -> f16 MFMA B-frag layout in ws ----------------
// ws[gt*1024 + lane*16] : f16x8 frag, B[k = (lane>>4)*8 + j][n = gt*16+(lane&15)]
// ws + 288*1024 : float bias[4608] (log2e-scaled)
__global__ __launch_bounds__(64)
void nomc_prep(const float* __restrict__ Wj, const float* __restrict__ bj,
               const float* __restrict__ Wr, const float* __restrict__ br,
               void* __restrict__ ws)
{
    const int gt = blockIdx.x;           // 0..287
    const int l = threadIdx.x, q = l >> 4, l15 = l & 15;
    const float* src; const float* bsrc; int stride;
    if (gt < 256) { const int n = gt * 16 + l15;        src = Wr + n; bsrc = br + n; stride = 4096; }
    else          { const int n = (gt - 256) * 16 + l15; src = Wj + n; bsrc = bj + n; stride = 512; }
    V8 v;
#pragma unroll
    for (int j = 0; j < 4; ++j) {
        const float f0 = src[(q * 8 + 2 * j)     * stride] * LOG2E;
        const float f1 = src[(q * 8 + 2 * j + 1) * stride] * LOG2E;
        v.p[j] = __builtin_amdgcn_cvt_pkrtz(f0, f1);
    }
    *(i32x4*)((char*)ws + (size_t)gt * 1024 + l * 16) = v.i;
    if (l < 16)
        ((float*)((char*)ws + NTILE * 1024))[gt * 16 + l] = bsrc[0] * LOG2E;
}

// ---------------- main ----------------
__global__ __launch_bounds__(1024, 4)
void nomc_main(const float* __restrict__ x_m, const float* __restrict__ x_a,
               const float* __restrict__ Wo, const float* __restrict__ bo,
               const float* __restrict__ Wfc, const float* __restrict__ bfc,
               const void* __restrict__ ws, float* __restrict__ out)
{
    const int b = blockIdx.x, tid = threadIdx.x;
    const int w = tid >> 6, l = tid & 63, q = l >> 4, l15 = l & 15;

    __shared__ __align__(16) __fp16 RT[16][8][64][8];   // 131072 B  RT[t][h>>3][k][h&7]=e
    __shared__ __align__(16) __fp16 JT[16][64][8];      //  16384 B  JT[t][k][m]=e_j
    __shared__ float sinv[16][64];                      //   4096 B  1/rowsum(R)
    __shared__ __align__(16) __fp16 xj[16][32];         //   1024 B  [t][m]=xm/s, [8..31]=0
    __shared__ float xm_lds[T_][M_];                    //   8192 B
    __shared__ __align__(16) __fp16 cbuf[64];           //    128 B  c-hat staging (A-frag)
    __shared__ float cfin_lds[H_];                      //    256 B
    // total 161152 <= 163840

    {   // stage x_m; zero the xj pad (slots 8..31 must be 0 every launch)
        const float* xmb = x_m + (size_t)b * T_ * M_;
        for (int i = tid; i < T_ * M_; i += 1024) (&xm_lds[0][0])[i] = xmb[i];
        for (int i = tid; i < 16 * 32; i += 1024) (&xj[0][0])[i] = (__fp16)0.f;
    }
    __syncthreads();

    // wave w owns groups [g0, g0+ngrp); group = 4 tiles = one full softmax row.
    // waves 0..13 -> R rows (gg 0..63); waves 14,15 -> J rows (gg 64..71).
    const int ngrp = (w < 8) ? 5 : 4;
    const int g0   = (w < 8) ? w * 5 : 40 + (w - 8) * 4;
    const char* wsb = (const char*)ws;
    const float* wbias = (const float*)(wsb + NTILE * 1024);

    float c0 = 0.f, c1 = 0.f, c2 = 0.f, c3 = 0.f;   // c[kt*16 + l15]

    for (int it = 0; it < 16; ++it) {
        // ================= produce: 16 timesteps of exp(logits) =================
        V8 af;
        {   // A-frag: row = l15 -> t = it*16+l15; k = q*8+j
            const float* xa = x_a + ((size_t)b * T_ + it * 16 + l15) * AUX_ + q * 8;
            const f32x4 x0 = *(const f32x4*)xa;
            const f32x4 x1 = *(const f32x4*)(xa + 4);
            af.p[0] = __builtin_amdgcn_cvt_pkrtz(x0.x, x0.y);
            af.p[1] = __builtin_amdgcn_cvt_pkrtz(x0.z, x0.w);
            af.p[2] = __builtin_amdgcn_cvt_pkrtz(x1.x, x1.y);
            af.p[3] = __builtin_amdgcn_cvt_pkrtz(x1.z, x1.w);
        }

        for (int g = 0; g < ngrp; ++g) {
            const int gg = g0 + g;                       // 0..63 R row h; 64..71 J row m
            float es0 = 0.f, es1 = 0.f, es2 = 0.f, es3 = 0.f;
#pragma unroll
            for (int tt = 0; tt < 4; ++tt) {
                const int gt = gg * 4 + tt;
                V8 bf; bf.i = *(const i32x4*)(wsb + (size_t)gt * 1024 + l * 16);
                const float bv = wbias[gt * 16 + l15];
                f32x4 acc = {bv, bv, bv, bv};
                acc = MFMA16(af.v, bf.v, acc);
                const float e0 = EXP2(acc[0]), e1 = EXP2(acc[1]);
                const float e2 = EXP2(acc[2]), e3 = EXP2(acc[3]);
                const int kk = (tt << 4) + l15;
                if (gg < 64) {
                    const int hb = gg >> 3, p = gg & 7;  // plain layout (r10)
                    RT[q * 4 + 0][hb][kk][p] = (__fp16)e0;
                    RT[q * 4 + 1][hb][kk][p] = (__fp16)e1;
                    RT[q * 4 + 2][hb][kk][p] = (__fp16)e2;
                    RT[q * 4 + 3][hb][kk][p] = (__fp16)e3;
                } else {
                    const int mp = gg - 64;
                    JT[q * 4 + 0][kk][mp] = (__fp16)e0;
                    JT[q * 4 + 1][kk][mp] = (__fp16)e1;
                    JT[q * 4 + 2][kk][mp] = (__fp16)e2;
                    JT[q * 4 + 3][kk][mp] = (__fp16)e3;
                }
                es0 += e0; es1 += e1; es2 += e2; es3 += e3;
            }
            const float sr0 = sum16_all(es0), sr1 = sum16_all(es1);
            const float sr2 = sum16_all(es2), sr3 = sum16_all(es3);
            if (l15 == 0) {
                if (gg < 64) {
                    sinv[q * 4 + 0][gg] = __builtin_amdgcn_rcpf(sr0);
                    sinv[q * 4 + 1][gg] = __builtin_amdgcn_rcpf(sr1);
                    sinv[q * 4 + 2][gg] = __builtin_amdgcn_rcpf(sr2);
                    sinv[q * 4 + 3][gg] = __builtin_amdgcn_rcpf(sr3);
                } else {
                    const int m = gg - 64;
                    xj[q * 4 + 0][m] = (__fp16)(xm_lds[it * 16 + q * 4 + 0][m] * __builtin_amdgcn_rcpf(sr0));
                    xj[q * 4 + 1][m] = (__fp16)(xm_lds[it * 16 + q * 4 + 1][m] * __builtin_amdgcn_rcpf(sr1));
                    xj[q * 4 + 2][m] = (__fp16)(xm_lds[it * 16 + q * 4 + 2][m] * __builtin_amdgcn_rcpf(sr2));
                    xj[q * 4 + 3][m] = (__fp16)(xm_lds[it * 16 + q * 4 + 3][m] * __builtin_amdgcn_rcpf(sr3));
                }
            }
        }
        __syncthreads();

        // ================= scan: 16 serial MFMA matvecs (wave 15) =================
        if (w == 15) {
            float sv = sinv[0][l];                       // per-window head load
            for (int u = 0; u < 16; ++u) {
                // ALL lanes write (r10-verified handoff pattern)
                const float cown = (q == 0) ? c0 : (q == 1) ? c1 : (q == 2) ? c2 : c3;
                cbuf[l] = (__fp16)(cown * sv);
                // --- junction block: independent of cbuf, hides the write drain ---
                V8 xjA; xjA.v = *(const f16x8*)&xj[u][q * 8];
                V8 j0, j1, j2, j3;
                j0.v = *(const f16x8*)&JT[u][l15][0];
                j1.v = *(const f16x8*)&JT[u][16 + l15][0];
                j2.v = *(const f16x8*)&JT[u][32 + l15][0];
                j3.v = *(const f16x8*)&JT[u][48 + l15][0];
                f32x4 a0 = {0.f, 0.f, 0.f, 0.f}, a1 = a0, a2 = a0, a3 = a0;
                a0 = MFMA16(xjA.v, j0.v, a0);
                a1 = MFMA16(xjA.v, j1.v, a1);
                a2 = MFMA16(xjA.v, j2.v, a2);
                a3 = MFMA16(xjA.v, j3.v, a3);
                LDS_FENCE();                             // write visible before A reads
                V8 A0; A0.v = *(const f16x8*)&cbuf[q * 8];
                V8 A1; A1.v = *(const f16x8*)&cbuf[32 + q * 8];
                if (u < 15) sv = sinv[u + 1][l];         // pipelined next sinv
                // --- R chain, depth 2 per kt (accJ precomputed) ---
                V8 b0, b1;
                b0.v = *(const f16x8*)&RT[u][q][l15][0];
                b1.v = *(const f16x8*)&RT[u][4 + q][l15][0];
                a0 = MFMA16(A0.v, b0.v, a0);
                a0 = MFMA16(A1.v, b1.v, a0);
                b0.v = *(const f16x8*)&RT[u][q][16 + l15][0];
                b1.v = *(const f16x8*)&RT[u][4 + q][16 + l15][0];
                a1 = MFMA16(A0.v, b0.v, a1);
                a1 = MFMA16(A1.v, b1.v, a1);
                b0.v = *(const f16x8*)&RT[u][q][32 + l15][0];
                b1.v = *(const f16x8*)&RT[u][4 + q][32 + l15][0];
                a2 = MFMA16(A0.v, b0.v, a2);
                a2 = MFMA16(A1.v, b1.v, a2);
                b0.v = *(const f16x8*)&RT[u][q][48 + l15][0];
                b1.v = *(const f16x8*)&RT[u][4 + q][48 + l15][0];
                a3 = MFMA16(A0.v, b0.v, a3);
                a3 = MFMA16(A1.v, b1.v, a3);
                c0 = a0[0]; c1 = a1[0]; c2 = a2[0]; c3 = a3[0];
                C_FENCE();                               // no cross-iteration hoisting
            }
        }
        __syncthreads();
    }

    // ---- epilogue: out = (sigmoid(xa_T@Wo+bo) * c_T) @ Wfc + bfc ----
    if (w == 15) {
        const float cown = (q == 0) ? c0 : (q == 1) ? c1 : (q == 2) ? c2 : c3;
        cfin_lds[l] = cown;                              // all-lane write
        LDS_FENCE();
        const float* xa = x_a + ((size_t)b * T_ + (T_ - 1)) * AUX_;
        float L = bo[l];
#pragma unroll
        for (int a = 0; a < AUX_; ++a) L = fmaf(xa[a], Wo[a * H_ + l], L);
        const float o = 1.0f / (1.0f + __expf(-L));
        const float cfin = cfin_lds[l];
        float p = (o * cfin) * Wfc[l];
        p = sum64_uni(p);
        if (l == 0) out[b] = p + bfc[0];
        out[B_ + b * H_ + l] = cfin;                     // c_final, coalesced
    }
}

} // namespace

extern "C" void kernel_launch(void* const* d_in, const int* in_sizes, int n_in,
                              void* d_out, int out_size, void* d_ws, size_t ws_size,
                              hipStream_t stream) {
    const float* x_m = (const float*)d_in[0];
    const float* x_a = (const float*)d_in[1];
    const float* Wj  = (const float*)d_in[2];
    const float* bj  = (const float*)d_in[3];
    const float* Wr  = (const float*)d_in[4];
    const float* br  = (const float*)d_in[5];
    const float* Wo  = (const float*)d_in[6];
    const float* bo  = (const float*)d_in[7];
    const float* Wfc = (const float*)d_in[8];
    const float* bfc = (const float*)d_in[9];
    float* out = (float*)d_out;

    hipLaunchKernelGGL(nomc_prep, dim3(NTILE), dim3(64), 0, stream,
                       Wj, bj, Wr, br, d_ws);
    hipLaunchKernelGGL(nomc_main, dim3(B_), dim3(1024), 0, stream,
                       x_m, x_a, Wo, bo, Wfc, bfc, d_ws, out);
}

// Round 14
// 262.179 us; speedup vs baseline: 1.2117x; 1.0725x over previous
//
#include <hip/hip_runtime.h>

// NoMCOutModel round 14: r10's verified structure, with the junction inflow
// REMOVED from the serial scan loop. m_in[t][k] = sum_m (xm/s_j)*e_j[t][m][k]
// is c-independent -> computed by a parallel 1024-thread pass after the
// produce barrier (t=wave, k=lane; JT+xj b128 reads, 4 fdot2, f16 store to
// minL[16][64]). Scan step drops the junction MFMA + its 5 LDS reads: per kt
// acc inits from m_in (C-operand), then the 2-deep R chain. The r10 step
// SHAPE is otherwise untouched (r12's swizzle and r13's reordering both
// regressed the serial wave; r10's step is locally optimal).
// Produce phase: r10 exact (plain layout; store conflicts are absorbed by
// 15-wave TLP, off the critical path -- r12 measured).

namespace {

constexpr int B_ = 256, T_ = 256, M_ = 8, AUX_ = 32, H_ = 64;
constexpr int NTILE = 288;               // (64*64 + 8*64)/16 logit col-tiles
constexpr float LOG2E = 1.4426950408889634f;

typedef __fp16 f16x2 __attribute__((ext_vector_type(2)));
typedef __fp16 f16x8 __attribute__((ext_vector_type(8)));
typedef float  f32x4 __attribute__((ext_vector_type(4)));
typedef int    i32x4 __attribute__((ext_vector_type(4)));

union V8 { f16x8 v; f16x2 p[4]; i32x4 i; };

#if __has_builtin(__builtin_amdgcn_exp2f)
#define EXP2(x) __builtin_amdgcn_exp2f(x)
#else
#define EXP2(x) exp2f(x)
#endif

#define MFMA16(A, Bv, C) __builtin_amdgcn_mfma_f32_16x16x32_f16((A), (Bv), (C), 0, 0, 0)

__device__ __forceinline__ float dot2(f16x2 a, f16x2 b, float c) {
    return __builtin_amdgcn_fdot2(a, b, c, false);
}

template <int CTRL>
__device__ __forceinline__ float dpp_add(float v) {
    int t = __builtin_amdgcn_update_dpp(0, __builtin_bit_cast(int, v),
                                        CTRL, 0xf, 0xf, true);
    return v + __builtin_bit_cast(float, t);
}
__device__ __forceinline__ float sum16_all(float v) {
    v = dpp_add<0xB1>(v);   // quad_perm [1,0,3,2]
    v = dpp_add<0x4E>(v);   // quad_perm [2,3,0,1]
    v = dpp_add<0x141>(v);  // row_half_mirror
    v = dpp_add<0x140>(v);  // row_mirror
    return v;
}
__device__ __forceinline__ float sum64_uni(float v) {
    v = dpp_add<0x111>(v); v = dpp_add<0x112>(v); v = dpp_add<0x114>(v);
    v = dpp_add<0x118>(v); v = dpp_add<0x142>(v); v = dpp_add<0x143>(v);
    return __builtin_bit_cast(float,
        __builtin_amdgcn_readlane(__builtin_bit_cast(int, v), 63));
}

#define LDS_FENCE() __asm__ volatile("s_waitcnt lgkmcnt(0)" ::: "memory")
#define C_FENCE()   __asm__ volatile("" ::: "memory")

// ---------------- prep: W -> f16 MFMA B-frag layout in ws ----------------
// ws[gt*1024 + lane*16] : f16x8 frag, B[k = (lane>>4)*8 + j][n = gt*16+(lane&15)]
// ws + 288*1024 : float bias[4608] (log2e-scaled)
__global__ __launch_bounds__(64)
void nomc_prep(const float* __restrict__ Wj, const float* __restrict__ bj,
               const float* __restrict__ Wr, const float* __restrict__ br,
               void* __restrict__ ws)
{
    const int gt = blockIdx.x;           // 0..287
    const int l = threadIdx.x, q = l >> 4, l15 = l & 15;
    const float* src; const float* bsrc; int stride;
    if (gt < 256) { const int n = gt * 16 + l15;        src = Wr + n; bsrc = br + n; stride = 4096; }
    else          { const int n = (gt - 256) * 16 + l15; src = Wj + n; bsrc = bj + n; stride = 512; }
    V8 v;
#pragma unroll
    for (int j = 0; j < 4; ++j) {
        const float f0 = src[(q * 8 + 2 * j)     * stride] * LOG2E;
        const float f1 = src[(q * 8 + 2 * j + 1) * stride] * LOG2E;
        v.p[j] = __builtin_amdgcn_cvt_pkrtz(f0, f1);
    }
    *(i32x4*)((char*)ws + (size_t)gt * 1024 + l * 16) = v.i;
    if (l < 16)
        ((float*)((char*)ws + NTILE * 1024))[gt * 16 + l] = bsrc[0] * LOG2E;
}

// ---------------- main ----------------
__global__ __launch_bounds__(1024, 4)
void nomc_main(const float* __restrict__ x_m, const float* __restrict__ x_a,
               const float* __restrict__ Wo, const float* __restrict__ bo,
               const float* __restrict__ Wfc, const float* __restrict__ bfc,
               const void* __restrict__ ws, float* __restrict__ out)
{
    const int b = blockIdx.x, tid = threadIdx.x;
    const int w = tid >> 6, l = tid & 63, q = l >> 4, l15 = l & 15;

    __shared__ __align__(16) __fp16 RT[16][8][64][8];   // 131072 B  RT[t][h>>3][k][h&7]=e
    __shared__ __align__(16) __fp16 JT[16][64][8];      //  16384 B  JT[t][k][m]=e_j
    __shared__ float sinv[16][64];                      //   4096 B  1/rowsum(R)
    __shared__ __align__(16) __fp16 xj[16][8];          //    256 B  [t][m]=xm/s_j
    __shared__ __align__(16) __fp16 minL[16][64];       //   2048 B  m_in[t][k]
    __shared__ float xm_lds[T_][M_];                    //   8192 B
    __shared__ __align__(16) __fp16 cbuf[64];           //    128 B  c-hat staging (A-frag)
    __shared__ float cfin_lds[H_];                      //    256 B
    // total 162432 <= 163840

    {   // stage x_m once
        const float* xmb = x_m + (size_t)b * T_ * M_;
        for (int i = tid; i < T_ * M_; i += 1024) (&xm_lds[0][0])[i] = xmb[i];
    }
    __syncthreads();

    // wave w owns groups [g0, g0+ngrp); group = 4 tiles = one full softmax row.
    // waves 0..13 -> R rows (gg 0..63); waves 14,15 -> J rows (gg 64..71).
    const int ngrp = (w < 8) ? 5 : 4;
    const int g0   = (w < 8) ? w * 5 : 40 + (w - 8) * 4;
    const char* wsb = (const char*)ws;
    const float* wbias = (const float*)(wsb + NTILE * 1024);

    float c0 = 0.f, c1 = 0.f, c2 = 0.f, c3 = 0.f;   // c[kt*16 + l15]

    for (int it = 0; it < 16; ++it) {
        // ================= produce: 16 timesteps of exp(logits) =================
        V8 af;
        {   // A-frag: row = l15 -> t = it*16+l15; k = q*8+j
            const float* xa = x_a + ((size_t)b * T_ + it * 16 + l15) * AUX_ + q * 8;
            const f32x4 x0 = *(const f32x4*)xa;
            const f32x4 x1 = *(const f32x4*)(xa + 4);
            af.p[0] = __builtin_amdgcn_cvt_pkrtz(x0.x, x0.y);
            af.p[1] = __builtin_amdgcn_cvt_pkrtz(x0.z, x0.w);
            af.p[2] = __builtin_amdgcn_cvt_pkrtz(x1.x, x1.y);
            af.p[3] = __builtin_amdgcn_cvt_pkrtz(x1.z, x1.w);
        }

        for (int g = 0; g < ngrp; ++g) {
            const int gg = g0 + g;                       // 0..63 R row h; 64..71 J row m
            float es0 = 0.f, es1 = 0.f, es2 = 0.f, es3 = 0.f;
#pragma unroll
            for (int tt = 0; tt < 4; ++tt) {
                const int gt = gg * 4 + tt;
                V8 bf; bf.i = *(const i32x4*)(wsb + (size_t)gt * 1024 + l * 16);
                const float bv = wbias[gt * 16 + l15];
                f32x4 acc = {bv, bv, bv, bv};
                acc = MFMA16(af.v, bf.v, acc);
                const float e0 = EXP2(acc[0]), e1 = EXP2(acc[1]);
                const float e2 = EXP2(acc[2]), e3 = EXP2(acc[3]);
                const int kk = (tt << 4) + l15;
                if (gg < 64) {
                    const int hb = gg >> 3, p = gg & 7;  // plain layout (r10)
                    RT[q * 4 + 0][hb][kk][p] = (__fp16)e0;
                    RT[q * 4 + 1][hb][kk][p] = (__fp16)e1;
                    RT[q * 4 + 2][hb][kk][p] = (__fp16)e2;
                    RT[q * 4 + 3][hb][kk][p] = (__fp16)e3;
                } else {
                    const int mp = gg - 64;
                    JT[q * 4 + 0][kk][mp] = (__fp16)e0;
                    JT[q * 4 + 1][kk][mp] = (__fp16)e1;
                    JT[q * 4 + 2][kk][mp] = (__fp16)e2;
                    JT[q * 4 + 3][kk][mp] = (__fp16)e3;
                }
                es0 += e0; es1 += e1; es2 += e2; es3 += e3;
            }
            const float sr0 = sum16_all(es0), sr1 = sum16_all(es1);
            const float sr2 = sum16_all(es2), sr3 = sum16_all(es3);
            if (l15 == 0) {
                if (gg < 64) {
                    sinv[q * 4 + 0][gg] = __builtin_amdgcn_rcpf(sr0);
                    sinv[q * 4 + 1][gg] = __builtin_amdgcn_rcpf(sr1);
                    sinv[q * 4 + 2][gg] = __builtin_amdgcn_rcpf(sr2);
                    sinv[q * 4 + 3][gg] = __builtin_amdgcn_rcpf(sr3);
                } else {
                    const int m = gg - 64;
                    xj[q * 4 + 0][m] = (__fp16)(xm_lds[it * 16 + q * 4 + 0][m] * __builtin_amdgcn_rcpf(sr0));
                    xj[q * 4 + 1][m] = (__fp16)(xm_lds[it * 16 + q * 4 + 1][m] * __builtin_amdgcn_rcpf(sr1));
                    xj[q * 4 + 2][m] = (__fp16)(xm_lds[it * 16 + q * 4 + 2][m] * __builtin_amdgcn_rcpf(sr2));
                    xj[q * 4 + 3][m] = (__fp16)(xm_lds[it * 16 + q * 4 + 3][m] * __builtin_amdgcn_rcpf(sr3));
                }
            }
        }
        __syncthreads();

        // ====== m_in pass (parallel, c-independent): minL[t][k] = xj[t].JT[t][k] ======
        {
            V8 jv; jv.v = *(const f16x8*)&JT[w][l][0];
            V8 xv; xv.v = *(const f16x8*)&xj[w][0];
            float s = 0.f;
            s = dot2(jv.p[0], xv.p[0], s);
            s = dot2(jv.p[1], xv.p[1], s);
            s = dot2(jv.p[2], xv.p[2], s);
            s = dot2(jv.p[3], xv.p[3], s);
            minL[w][l] = (__fp16)s;
        }
        __syncthreads();

        // ================= scan: 16 serial MFMA matvecs (wave 15) =================
        if (w == 15) {
            for (int u = 0; u < 16; ++u) {
                const float cown = (q == 0) ? c0 : (q == 1) ? c1 : (q == 2) ? c2 : c3;
                // m_in reads are cbuf-independent; issue before the fence
                const float mi0 = (float)minL[u][l15];
                const float mi1 = (float)minL[u][16 + l15];
                const float mi2 = (float)minL[u][32 + l15];
                const float mi3 = (float)minL[u][48 + l15];
                cbuf[l] = (__fp16)(cown * sinv[u][l]);   // r10-verified handoff
                LDS_FENCE();                             // write visible before A reads
                V8 A0; A0.v = *(const f16x8*)&cbuf[q * 8];
                V8 A1; A1.v = *(const f16x8*)&cbuf[32 + q * 8];
                float cn0, cn1, cn2, cn3;
                {
                    V8 b0; b0.v = *(const f16x8*)&RT[u][q][l15][0];
                    V8 b1; b1.v = *(const f16x8*)&RT[u][4 + q][l15][0];
                    f32x4 acc = {mi0, mi0, mi0, mi0};
                    acc = MFMA16(A0.v, b0.v, acc);
                    acc = MFMA16(A1.v, b1.v, acc);
                    cn0 = acc[0];
                }
                {
                    V8 b0; b0.v = *(const f16x8*)&RT[u][q][16 + l15][0];
                    V8 b1; b1.v = *(const f16x8*)&RT[u][4 + q][16 + l15][0];
                    f32x4 acc = {mi1, mi1, mi1, mi1};
                    acc = MFMA16(A0.v, b0.v, acc);
                    acc = MFMA16(A1.v, b1.v, acc);
                    cn1 = acc[0];
                }
                {
                    V8 b0; b0.v = *(const f16x8*)&RT[u][q][32 + l15][0];
                    V8 b1; b1.v = *(const f16x8*)&RT[u][4 + q][32 + l15][0];
                    f32x4 acc = {mi2, mi2, mi2, mi2};
                    acc = MFMA16(A0.v, b0.v, acc);
                    acc = MFMA16(A1.v, b1.v, acc);
                    cn2 = acc[0];
                }
                {
                    V8 b0; b0.v = *(const f16x8*)&RT[u][q][48 + l15][0];
                    V8 b1; b1.v = *(const f16x8*)&RT[u][4 + q][48 + l15][0];
                    f32x4 acc = {mi3, mi3, mi3, mi3};
                    acc = MFMA16(A0.v, b0.v, acc);
                    acc = MFMA16(A1.v, b1.v, acc);
                    cn3 = acc[0];
                }
                c0 = cn0; c1 = cn1; c2 = cn2; c3 = cn3;
                C_FENCE();                               // no cross-iteration hoisting
            }
        }
        __syncthreads();
    }

    // ---- epilogue: out = (sigmoid(xa_T@Wo+bo) * c_T) @ Wfc + bfc ----
    if (w == 15) {
        const float cown = (q == 0) ? c0 : (q == 1) ? c1 : (q == 2) ? c2 : c3;
        cfin_lds[l] = cown;                              // all-lane write
        LDS_FENCE();
        const float* xa = x_a + ((size_t)b * T_ + (T_ - 1)) * AUX_;
        float L = bo[l];
#pragma unroll
        for (int a = 0; a < AUX_; ++a) L = fmaf(xa[a], Wo[a * H_ + l], L);
        const float o = 1.0f / (1.0f + __expf(-L));
        const float cfin = cfin_lds[l];
        float p = (o * cfin) * Wfc[l];
        p = sum64_uni(p);
        if (l == 0) out[b] = p + bfc[0];
        out[B_ + b * H_ + l] = cfin;                     // c_final, coalesced
    }
}

} // namespace

extern "C" void kernel_launch(void* const* d_in, const int* in_sizes, int n_in,
                              void* d_out, int out_size, void* d_ws, size_t ws_size,
                              hipStream_t stream) {
    const float* x_m = (const float*)d_in[0];
    const float* x_a = (const float*)d_in[1];
    const float* Wj  = (const float*)d_in[2];
    const float* bj  = (const float*)d_in[3];
    const float* Wr  = (const float*)d_in[4];
    const float* br  = (const float*)d_in[5];
    const float* Wo  = (const float*)d_in[6];
    const float* bo  = (const float*)d_in[7];
    const float* Wfc = (const float*)d_in[8];
    const float* bfc = (const float*)d_in[9];
    float* out = (float*)d_out;

    hipLaunchKernelGGL(nomc_prep, dim3(NTILE), dim3(64), 0, stream,
                       Wj, bj, Wr, br, d_ws);
    hipLaunchKernelGGL(nomc_main, dim3(B_), dim3(1024), 0, stream,
                       x_m, x_a, Wo, bo, Wfc, bfc, d_ws, out);
}